// Round 7
// baseline (316.065 us; speedup 1.0000x reference)
//
#include <hip/hip_runtime.h>

#define START_TAG 62
#define STOP_TAG 63
#define BATCH 512
#define SLEN 1024
#define NCHAIN 64        // 32 groups x 2 directions
#define RING 16          // e-ring slots (power of 2: slot math = AND)
#define SLOTB 4096       // bytes per slot: 64 lanes x 64B (16 f32 e-values per lane)

typedef float vf4 __attribute__((ext_vector_type(4)));
typedef short short8 __attribute__((ext_vector_type(8)));

__device__ __forceinline__ unsigned pk_bf16(float lo, float hi) {
  return __builtin_amdgcn_perm(__float_as_uint(hi), __float_as_uint(lo), 0x07060302u);
}
__device__ __forceinline__ short bf16_rne(float x) {
  unsigned u = __float_as_uint(x);
  u += 0x7FFFu + ((u >> 16) & 1u);
  return (short)(u >> 16);
}
__device__ __forceinline__ vf4 mfma16(short8 a, short8 b, vf4 c) {
  return __builtin_amdgcn_mfma_f32_16x16x32_bf16(a, b, c, 0, 0, 0);
}

// ---- A fragments: E (fwd) / E^T (bwd) in bf16, custom tag<->slot map (R3..R6-verified) ----
template<int DIR>
__device__ __forceinline__ void load_A(const float* __restrict__ trans, short8 A[4][2],
                                       int q, int col) {
  const int mrow = 16 * (col >> 2) + (col & 3);
  #pragma unroll
  for (int t = 0; t < 4; ++t) {
    #pragma unroll
    for (int c = 0; c < 2; ++c) {
      short8 a;
      #pragma unroll
      for (int j = 0; j < 8; ++j) {
        int R = mrow + 4 * t, K = 16 * q + 8 * c + j;
        float tv = (DIR == 0) ? trans[R * 64 + K] : trans[K * 64 + R];
        a[j] = bf16_rne(__expf(tv));
      }
      A[t][c] = a;
    }
  }
}

template<int DIR>
__device__ __forceinline__ void epilogue(float* __restrict__ ws, const float W[16],
                                         float C, int g, int lane, int q, int col) {
  float* slab = ws + (size_t)(g * 2 + DIR) * 1024;
  #pragma unroll
  for (int t4 = 0; t4 < 4; ++t4) {
    vf4 o = {W[t4 * 4], W[t4 * 4 + 1], W[t4 * 4 + 2], W[t4 * 4 + 3]};
    *(vf4*)(slab + lane * 16 + t4 * 4) = o;
  }
  if (q == 0) ws[65536 + (g * 2 + DIR) * 16 + col] = C;
}

// ---- producer wave pid (1..3): computes e=exp(feat) for steps j ≡ pid-1 (mod 3),
// writes f32 e-vectors into the LDS ring, sets flags[slot]=j+1 after lgkm drain.
template<int DIR>
__device__ __forceinline__ void producer(const float* __restrict__ feats, char* sm,
                                         int* flags, volatile int* cprog, int g, int pid) {
  const int lane = threadIdx.x & 63;
  const int q = lane >> 4, col = lane & 15;
  const int b = g * 16 + col;
  const float* fb = feats + (size_t)b * 65536 + q * 16;

  int j = pid - 1;
  vf4 L[4];
  {
    size_t s = (size_t)(DIR ? 1023 - j : j);
    #pragma unroll
    for (int v = 0; v < 4; ++v) L[v] = *(const vf4*)(fb + s * 64 + v * 4);
  }
  int cp = -1;
  while (j <= 515) {
    int nj = j + 3;
    vf4 N[4] = {L[0], L[1], L[2], L[3]};
    if (nj <= 515) {                       // prefetch next handled step
      int sc = nj > 511 ? 511 : nj;        // clamp: steps 512..515 are dummies
      size_t s = (size_t)(DIR ? 1023 - sc : sc);
      #pragma unroll
      for (int v = 0; v < 4; ++v) N[v] = *(const vf4*)(fb + s * 64 + v * 4);
    }
    if (j >= RING) {                       // back-pressure: consumer done with step j-16
      while (cp < j - RING) cp = *cprog;
    }
    vf4 ev[4];
    #pragma unroll
    for (int v = 0; v < 4; ++v)
      #pragma unroll
      for (int i = 0; i < 4; ++i) ev[v][i] = __expf(L[v][i]);
    char* sb = sm + (j & 15) * SLOTB;
    #pragma unroll
    for (int v = 0; v < 4; ++v)
      *(vf4*)(sb + v * 1024 + lane * 16) = ev[v];
    asm volatile("s_waitcnt lgkmcnt(0)" ::: "memory");   // data visible before flag
    if (lane == 0) *(volatile int*)(flags + (j & 15)) = j + 1;
    #pragma unroll
    for (int v = 0; v < 4; ++v) L[v] = N[v];
    j = nj;
  }
}

// ---- consumer wave: the serial chain. e arrives precomputed (f32) from the ring.
template<int DIR>
__device__ __forceinline__ void consumer(const float* __restrict__ trans,
                                         float* __restrict__ ws, char* sm,
                                         int* flags, int g) {
  const int lane = threadIdx.x & 63;
  const int q = lane >> 4, col = lane & 15;
  const int b = g * 16 + col;

  short8 A[4][2];
  load_A<DIR>(trans, A, q, col);

  float W[16];
  if (DIR == 0) {
    #pragma unroll
    for (int i = 0; i < 16; ++i) W[i] = 0.f;
    if (q == 3) W[14] = 1.f;               // true tag 62 = START
  } else {
    #pragma unroll
    for (int i = 0; i < 16; ++i) W[i] = __expf(trans[STOP_TAG * 64 + 16 * q + i]);
  }

  volatile int* vfl = (volatile int*)flags;
  // prime: slot 0 ready?
  while (vfl[0] != 1) {}
  asm volatile("" ::: "memory");
  vf4 ereg[4];
  #pragma unroll
  for (int v = 0; v < 4; ++v)
    ereg[v] = *(const vf4*)(sm + v * 1024 + lane * 16);
  int fl_next = vfl[1];

  float C = 0.f, zpend = 1.f;

  for (int bk = 0; bk < 32; ++bk) {
    #pragma unroll
    for (int u = 0; u < 16; ++u) {
      const int j = bk * 16 + u;
      // verify flag for slot (j+1) == j+2 (fetched one step ago; spin on miss)
      if (fl_next != j + 2) {
        while (fl_next != j + 2) fl_next = vfl[(u + 1) & 15];
      }
      asm volatile("" ::: "memory");
      // issue reads for step j+1 (latency hidden by one full step)
      const int rs = (u + 1) & 15;
      vf4 enxt[4];
      #pragma unroll
      for (int v = 0; v < 4; ++v)
        enxt[v] = *(const vf4*)(sm + rs * SLOTB + v * 1024 + lane * 16);
      int fl2 = vfl[(u + 2) & 15];          // speculative flag for slot j+2

      // ---- step j compute (R6-verified math), e = ereg ----
      float P[16];
      #pragma unroll
      for (int v = 0; v < 4; ++v)
        #pragma unroll
        for (int i = 0; i < 4; ++i)
          P[v * 4 + i] = (DIR == 0) ? W[v * 4 + i] : W[v * 4 + i] * ereg[v][i];

      union { unsigned uu[4]; short8 s8; } B0, B1;
      B0.uu[0] = pk_bf16(P[0], P[1]);   B0.uu[1] = pk_bf16(P[2], P[3]);
      B0.uu[2] = pk_bf16(P[4], P[5]);   B0.uu[3] = pk_bf16(P[6], P[7]);
      B1.uu[0] = pk_bf16(P[8], P[9]);   B1.uu[1] = pk_bf16(P[10], P[11]);
      B1.uu[2] = pk_bf16(P[12], P[13]); B1.uu[3] = pk_bf16(P[14], P[15]);

      vf4 z4 = {0.f, 0.f, 0.f, 0.f};
      vf4 d0 = mfma16(A[0][0], B0.s8, z4);
      vf4 d1 = mfma16(A[1][0], B0.s8, z4);
      vf4 d2 = mfma16(A[2][0], B0.s8, z4);
      vf4 d3 = mfma16(A[3][0], B0.s8, z4);
      d0 = mfma16(A[0][1], B1.s8, d0);
      d1 = mfma16(A[1][1], B1.s8, d1);
      d2 = mfma16(A[2][1], B1.s8, d2);
      d3 = mfma16(A[3][1], B1.s8, d3);

      #pragma unroll
      for (int i = 0; i < 4; ++i) {
        W[i]      = (DIR == 0) ? d0[i] * ereg[0][i] : d0[i];
        W[4 + i]  = (DIR == 0) ? d1[i] * ereg[1][i] : d1[i];
        W[8 + i]  = (DIR == 0) ? d2[i] * ereg[2][i] : d2[i];
        W[12 + i] = (DIR == 0) ? d3[i] * ereg[3][i] : d3[i];
      }

      fl_next = fl2;
      #pragma unroll
      for (int v = 0; v < 4; ++v) ereg[v] = enxt[v];

      if ((u & 3) == 3) {
        // pipelined renorm (R5-verified) + publish progress for producer back-pressure
        float rz = __builtin_amdgcn_rcpf(zpend);
        C += __logf(zpend);
        #pragma unroll
        for (int i = 0; i < 16; ++i) W[i] *= rz;
        zpend = __shfl(W[0], col);           // true-tag-0 weight of this column (> 0)
        if (lane == 0) *(volatile int*)(flags + 16) = j;
      }
    }
  }
  epilogue<DIR>(ws, W, C, g, lane, q, col);
}

// Masked fallback (general mask) — single wave, plain loads (R4-verified).
template<int DIR>
__device__ __forceinline__ void chain_masked(const float* __restrict__ feats,
                                             const float* __restrict__ trans,
                                             const int* __restrict__ mask,
                                             float* __restrict__ ws, int g) {
  const int lane = threadIdx.x & 63;
  const int q = lane >> 4, col = lane & 15;
  const int b = g * 16 + col;

  short8 A[4][2];
  load_A<DIR>(trans, A, q, col);

  float W[16];
  float C = 0.f;
  if (DIR == 0) {
    #pragma unroll
    for (int i = 0; i < 16; ++i) W[i] = 0.f;
    if (q == 3) W[14] = 1.f;
  } else {
    #pragma unroll
    for (int i = 0; i < 16; ++i) W[i] = __expf(trans[STOP_TAG * 64 + 16 * q + i]);
  }

  const char* gb = (const char*)feats + (size_t)b * 262144 + (size_t)q * 64;
  vf4 cur[4];
  {
    size_t s0 = (DIR == 0) ? 0 : 1023;
    #pragma unroll
    for (int v = 0; v < 4; ++v)
      cur[v] = *(const vf4*)(gb + s0 * 256 + (size_t)v * 16);
  }

  for (int grp = 0; grp < 128; ++grp) {
    #pragma unroll
    for (int u = 0; u < 4; ++u) {
      const int j = grp * 4 + u;
      float e[16];
      #pragma unroll
      for (int v = 0; v < 4; ++v)
        #pragma unroll
        for (int i = 0; i < 4; ++i) e[v * 4 + i] = __expf(cur[v][i]);

      float P[16];
      #pragma unroll
      for (int i = 0; i < 16; ++i) P[i] = (DIR == 0) ? W[i] : W[i] * e[i];

      union { unsigned uu[4]; short8 s8; } B0, B1;
      B0.uu[0] = pk_bf16(P[0], P[1]);   B0.uu[1] = pk_bf16(P[2], P[3]);
      B0.uu[2] = pk_bf16(P[4], P[5]);   B0.uu[3] = pk_bf16(P[6], P[7]);
      B1.uu[0] = pk_bf16(P[8], P[9]);   B1.uu[1] = pk_bf16(P[10], P[11]);
      B1.uu[2] = pk_bf16(P[12], P[13]); B1.uu[3] = pk_bf16(P[14], P[15]);

      vf4 z4 = {0.f, 0.f, 0.f, 0.f};
      vf4 d0 = mfma16(A[0][0], B0.s8, z4);
      vf4 d1 = mfma16(A[1][0], B0.s8, z4);
      vf4 d2 = mfma16(A[2][0], B0.s8, z4);
      vf4 d3 = mfma16(A[3][0], B0.s8, z4);
      d0 = mfma16(A[0][1], B1.s8, d0);
      d1 = mfma16(A[1][1], B1.s8, d1);
      d2 = mfma16(A[2][1], B1.s8, d2);
      d3 = mfma16(A[3][1], B1.s8, d3);

      int sj = (DIR == 0) ? j : 1023 - j;
      int m = mask[b * 1024 + sj];
      int sn = (DIR == 0) ? (j + 1) : 1023 - (j + 1);
      #pragma unroll
      for (int v = 0; v < 4; ++v)
        cur[v] = *(const vf4*)(gb + (size_t)sn * 256 + (size_t)v * 16);

      #pragma unroll
      for (int i = 0; i < 4; ++i) {
        float n0 = (DIR == 0) ? d0[i] * e[i]      : d0[i];
        float n1 = (DIR == 0) ? d1[i] * e[4 + i]  : d1[i];
        float n2 = (DIR == 0) ? d2[i] * e[8 + i]  : d2[i];
        float n3 = (DIR == 0) ? d3[i] * e[12 + i] : d3[i];
        W[i]      = m ? n0 : W[i];
        W[4 + i]  = m ? n1 : W[4 + i];
        W[8 + i]  = m ? n2 : W[8 + i];
        W[12 + i] = m ? n3 : W[12 + i];
      }
    }
    float z = __shfl(W[0], col);
    float rz = __builtin_amdgcn_rcpf(z);
    C += __logf(z);
    #pragma unroll
    for (int i = 0; i < 16; ++i) W[i] *= rz;
  }
  epilogue<DIR>(ws, W, C, g, lane, q, col);
}

// Blocks 0..63: chain blocks (4 waves: wave0 consumer, waves1-3 producers).
// Blocks 64..575: gold score for batch blk-64 (wave0 only).
__global__ __launch_bounds__(256, 1)
void crf_main(const float* __restrict__ feats, const float* __restrict__ trans,
              const int* __restrict__ tags, const int* __restrict__ mask,
              float* __restrict__ ws) {
  __shared__ char sm[RING * SLOTB + 128];
  const int blk = blockIdx.x;
  if (blk < NCHAIN) {
    int* flags = (int*)(sm + RING * SLOTB);       // [0..15] slot flags, [16] consumer progress
    const int g = blk >> 1, dir = blk & 1;
    const int wv = threadIdx.x >> 6;
    const int lane = threadIdx.x & 63;
    const int q = lane >> 4, col = lane & 15;
    if (threadIdx.x < 17) flags[threadIdx.x] = (threadIdx.x == 16) ? -1 : 0;
    __syncthreads();                              // flags visible before any producer write

    const int b = g * 16 + col;
    const int sB = dir ? 512 : 0;
    int anyz = 0;
    for (int it = 0; it < 32; ++it) {
      int4 v = *(const int4*)(mask + b * 1024 + sB + (it * 4 + q) * 4);
      anyz |= (v.x == 0) | (v.y == 0) | (v.z == 0) | (v.w == 0);
    }
    bool allones = (__ballot(anyz != 0) == 0ull);

    if (allones) {
      if (wv == 0) {
        if (dir == 0) consumer<0>(trans, ws, sm, flags, g);
        else          consumer<1>(trans, ws, sm, flags, g);
      } else {
        volatile int* cprog = (volatile int*)(flags + 16);
        if (dir == 0) producer<0>(feats, sm, flags, cprog, g, wv);
        else          producer<1>(feats, sm, flags, cprog, g, wv);
      }
    } else {
      if (wv == 0) {
        if (dir == 0) chain_masked<0>(feats, trans, mask, ws, g);
        else          chain_masked<1>(feats, trans, mask, ws, g);
      }
    }
    (void)tags;
  } else {
    if (threadIdx.x >= 64) return;
    const int b = blk - NCHAIN;
    const int* tb = tags + b * SLEN;
    const int* mb = mask + b * SLEN;
    const float* fbg = feats + (size_t)b * 65536;
    float acc = 0.f, cnt = 0.f;
    const int t = threadIdx.x;
    for (int k = 0; k < 16; ++k) {
      int s = t + k * 64;
      int cur = tb[s];
      int prev = (s == 0) ? START_TAG : tb[s - 1];
      float m = (float)mb[s];
      acc += m * (fbg[s * 64 + cur] + trans[cur * 64 + prev]);
      cnt += m;
    }
    #pragma unroll
    for (int o = 1; o < 64; o <<= 1) {
      acc += __shfl_xor(acc, o);
      cnt += __shfl_xor(cnt, o);
    }
    if (t == 0) {
      int last_idx = (int)(cnt + 0.5f);
      int last_tag = (last_idx == 0) ? START_TAG : tb[last_idx - 1];
      ws[66560 + b] = acc + trans[STOP_TAG * 64 + last_tag];
    }
  }
}

__global__ __launch_bounds__(512)
void crf_reduce(const float* __restrict__ ws, float* __restrict__ out) {
  __shared__ float s[512];
  const int t = threadIdx.x;
  const int g = t >> 4, col = t & 15;
  const float* Wf = ws + (size_t)(2 * g) * 1024;
  const float* Wb = ws + (size_t)(2 * g + 1) * 1024;
  float P = 0.f;
  #pragma unroll
  for (int q = 0; q < 4; ++q)
    #pragma unroll
    for (int i = 0; i < 16; ++i)
      P += Wf[(q * 16 + col) * 16 + i] * Wb[(q * 16 + col) * 16 + i];
  float sc = ws[65536 + (2 * g) * 16 + col] + ws[65536 + (2 * g + 1) * 16 + col] + __logf(P);
  s[t] = sc - ws[66560 + t];
  __syncthreads();
  for (int off = 256; off > 0; off >>= 1) {
    if (t < off) s[t] += s[t + off];
    __syncthreads();
  }
  if (t == 0) out[0] = s[0] * (1.f / 512.f);
}

extern "C" void kernel_launch(void* const* d_in, const int* in_sizes, int n_in,
                              void* d_out, int out_size, void* d_ws, size_t ws_size,
                              hipStream_t stream) {
  const float* feats = (const float*)d_in[0];
  const float* trans = (const float*)d_in[1];
  const int* tags = (const int*)d_in[2];
  const int* mask = (const int*)d_in[3];
  float* ws = (float*)d_ws;
  float* out = (float*)d_out;

  crf_main<<<NCHAIN + BATCH, 256, 0, stream>>>(feats, trans, tags, mask, ws);
  crf_reduce<<<1, 512, 0, stream>>>(ws, out);
}